// Round 5
// baseline (1188.829 us; speedup 1.0000x reference)
//
#include <hip/hip_runtime.h>
#include <math.h>

// Problem constants: B=2, S=256, IN=80, H=128, NC=40, WSEG=64, F2=256
// Output layout (floats): cls_out[2*256*40]=20480 @0, bin_out[2*256*2]=1024 @20480,
//                         bmask[2*256]=512 @21504, pred_scores[2] @22016

#define OFF_BIN 20480
#define OFF_BM  21504
#define OFF_PRED 22016

__device__ __forceinline__ float preluf(float x, float a) { return x >= 0.f ? x : a * x; }
__device__ __forceinline__ float sigf(float x) { return 1.f / (1.f + __expf(-x)); }
__device__ __forceinline__ float rdlane(float v, int l) {
    return __uint_as_float(__builtin_amdgcn_readlane(__float_as_uint(v), l));
}

// ---------------- input projection: pre[t][b][g] = bias[g] + sum_k in(b,t,k)*W[g][k]
// in(b,t,k) = k<Adim ? inA[((b*256)+t)*Adim+k] : inB[((b*256)+t)*(K-Adim)+(k-Adim)]
__global__ __launch_bounds__(256) void k_pre(const float* __restrict__ inA,
                                             const float* __restrict__ inB,
                                             int Adim, int K,
                                             const float* __restrict__ wih,
                                             const float* __restrict__ bias,
                                             float* __restrict__ out) {
    int g = (blockIdx.x >> 6) * 256 + threadIdx.x;   // 0..511 gate index
    int tb0 = (blockIdx.x & 63) * 8;                 // 8 (t,b) rows per block
    int Bdim = K - Adim;
    float bv = bias[g];
    float acc[8];
#pragma unroll
    for (int r = 0; r < 8; ++r) acc[r] = bv;
    for (int k = 0; k < K; ++k) {
        float wv = wih[(size_t)g * K + k];
#pragma unroll
        for (int r = 0; r < 8; ++r) {
            int tb = tb0 + r; int t = tb >> 1; int b = tb & 1;
            float xv = (k < Adim) ? inA[(size_t)(((b << 8) + t)) * Adim + k]
                                  : inB[(size_t)(((b << 8) + t)) * Bdim + (k - Adim)];
            acc[r] += wv * xv;
        }
    }
#pragma unroll
    for (int r = 0; r < 8; ++r) out[(size_t)(tb0 + r) * 512 + g] = acc[r];
}

// ---------------- LSTM scan: one block per (dir, batch). blockIdx = dir*2 + b.
// LDS-issue-minimized: wave w owns k-chunk c=w>>1; lane holds h[32c+(lane&31)]
// in a register. GEMV reads h via v_readlane (literal index, VALU pipe) -> zero
// ds_read in the inner loop. Partials cross waves through a double-buffered LDS
// array (1 write + 4 reads per wave per step, ONE barrier per step). Every
// thread redundantly computes the activation for its own unit u.
__global__ __launch_bounds__(512, 2) void k_lstm(const float* __restrict__ pre_f,
                                                 const float* __restrict__ pre_b,
                                                 const float* __restrict__ whh_f,
                                                 const float* __restrict__ whh_b,
                                                 float* __restrict__ hout_f,
                                                 float* __restrict__ hout_b) {
    const int dir = blockIdx.x >> 1;
    const int b = blockIdx.x & 1;
    const float* pre = dir ? pre_b : pre_f;
    const float* whh = dir ? whh_b : whh_f;
    float* hout = dir ? hout_b : hout_f;
    const int tid = threadIdx.x;
    const int wv = tid >> 6;            // wave 0..7
    const int c = wv >> 1;              // k-chunk 0..3 (wave-uniform)
    const int lane = tid & 63;
    const int gg = ((wv & 1) << 6) | lane;   // unit this thread's partials target
    const int u = (c << 5) + (lane & 31);    // unit this thread activates / holds h
    const int k0 = c << 5;
    const bool owner = ((wv & 1) == 0) && (lane < 32);

    float w[4][32];
#pragma unroll
    for (int j = 0; j < 4; ++j) {
#pragma unroll
        for (int k = 0; k < 32; k += 4) {
            float4 v = *(const float4*)(whh + (size_t)((j << 7) + gg) * 128 + k0 + k);
            w[j][k] = v.x; w[j][k + 1] = v.y; w[j][k + 2] = v.z; w[j][k + 3] = v.w;
        }
    }

    __shared__ float4 part[2][4][128];
    float hreg = 0.f;       // h[u]
    float cst = 0.f;        // c[u]

    // prefetch step-0 pre for unit u (all 4 gate types)
    int t0 = dir ? 255 : 0;
    const float* pp0 = pre + ((size_t)t0 * 2 + b) * 512;
    float p0 = pp0[u], p1 = pp0[128 + u], p2 = pp0[256 + u], p3 = pp0[384 + u];

    int buf = 0;
    for (int step = 0; step < 256; ++step) {
        int t = dir ? (255 - step) : step;
        float n0 = 0.f, n1 = 0.f, n2 = 0.f, n3 = 0.f;
        if (step < 255) {
            int tn = dir ? (254 - step) : (step + 1);
            const float* pp = pre + ((size_t)tn * 2 + b) * 512;
            n0 = pp[u]; n1 = pp[128 + u]; n2 = pp[256 + u]; n3 = pp[384 + u];
        }
        float a0 = 0.f, a1 = 0.f, a2 = 0.f, a3 = 0.f;
#pragma unroll
        for (int k = 0; k < 32; ++k) {
            float hk = rdlane(hreg, k);   // h[k0+k], broadcast from lane k (VALU)
            a0 += w[0][k] * hk;
            a1 += w[1][k] * hk;
            a2 += w[2][k] * hk;
            a3 += w[3][k] * hk;
        }
        part[buf][c][gg] = make_float4(a0, a1, a2, a3);
        __syncthreads();
        float4 q0 = part[buf][0][u], q1 = part[buf][1][u],
               q2 = part[buf][2][u], q3 = part[buf][3][u];
        float gi = p0 + ((q0.x + q1.x) + (q2.x + q3.x));
        float gf = p1 + ((q0.y + q1.y) + (q2.y + q3.y));
        float gG = p2 + ((q0.z + q1.z) + (q2.z + q3.z));
        float go = p3 + ((q0.w + q1.w) + (q2.w + q3.w));
        cst = sigf(gf) * cst + sigf(gi) * tanhf(gG);
        float h = sigf(go) * tanhf(cst);
        hreg = h;
        if (owner) hout[(size_t)(((b << 8) + t) << 7) + u] = h;
        p0 = n0; p1 = n1; p2 = n2; p3 = n3;
        buf ^= 1;
    }
}

// ---------------- concat layer-1 dirs -> rnn, cumsum over time -> cum
__global__ __launch_bounds__(256) void k_cum(const float* __restrict__ h1f,
                                             const float* __restrict__ h1b,
                                             float* __restrict__ rnn,
                                             float* __restrict__ cum) {
    int b = blockIdx.x, k = threadIdx.x;
    const float* src = (k < 128) ? h1f : h1b;
    int kk = k & 127;
    float run = 0.f;
#pragma unroll 8
    for (int t = 0; t < 256; ++t) {
        float v = src[(size_t)(((b << 8) + t) << 7) + kk];
        size_t o = (size_t)(((b << 8) + t) << 8) + k;
        rnn[o] = v;
        run += v;
        cum[o] = run;
    }
}

// ---------------- Pd[b,i,u] = b_s1[u] + prelu(rnn[b,i],a0) . W1[u, 256:512]
//                  Pe[b,j,u] =           prelu(rnn[b,j],a0) . W1[u, 512:768]
__global__ __launch_bounds__(256) void k_pde(const float* __restrict__ rnn,
                                             const float* __restrict__ ws1,
                                             const float* __restrict__ bs1,
                                             const float* __restrict__ a_s0,
                                             float* __restrict__ Pd,
                                             float* __restrict__ Pe) {
    int row = blockIdx.x;  // b*256+s
    __shared__ float pr[256];
    float a0 = a_s0[0];
    float v = rnn[(size_t)row * 256 + threadIdx.x];
    pr[threadIdx.x] = preluf(v, a0);
    __syncthreads();
    int t = threadIdx.x;
    if (t < 100) {
        const float* wr = ws1 + (size_t)t * 768 + 256;
        float acc = bs1[t];
#pragma unroll 4
        for (int k = 0; k < 256; ++k) acc += pr[k] * wr[k];
        Pd[(size_t)row * 100 + t] = acc;
    } else if (t >= 128 && t < 228) {
        int u = t - 128;
        const float* wr = ws1 + (size_t)u * 768 + 512;
        float acc = 0.f;
#pragma unroll 4
        for (int k = 0; k < 256; ++k) acc += pr[k] * wr[k];
        Pe[(size_t)row * 100 + u] = acc;
    }
}

// ---------------- cls / bin heads
__global__ __launch_bounds__(256) void k_head(const float* __restrict__ rnn,
                                              const float* ac0p, const float* __restrict__ wc1,
                                              const float* __restrict__ bc1, const float* ac1p,
                                              const float* __restrict__ wc2, const float* __restrict__ bc2,
                                              const float* ab0p, const float* __restrict__ wb1,
                                              const float* __restrict__ bb1, const float* ab1p,
                                              const float* __restrict__ wb2, const float* __restrict__ bb2,
                                              float* __restrict__ out) {
    int row = blockIdx.x;  // b*256+s
    int tid = threadIdx.x;
    __shared__ float xc[256], xb[256], hc[80], hb[80];
    float ac0 = ac0p[0], ac1 = ac1p[0], ab0 = ab0p[0], ab1 = ab1p[0];
    float v = rnn[(size_t)row * 256 + tid];
    xc[tid] = preluf(v, ac0);
    xb[tid] = preluf(v, ab0);
    __syncthreads();
    if (tid < 80) {
        const float* wr = wc1 + (size_t)tid * 256;
        float acc = bc1[tid];
#pragma unroll 4
        for (int k = 0; k < 256; ++k) acc += xc[k] * wr[k];
        hc[tid] = preluf(acc, ac1);
    } else if (tid >= 128 && tid < 208) {
        int u = tid - 128;
        const float* wr = wb1 + (size_t)u * 256;
        float acc = bb1[u];
#pragma unroll 4
        for (int k = 0; k < 256; ++k) acc += xb[k] * wr[k];
        hb[u] = preluf(acc, ab1);
    }
    __syncthreads();
    if (tid < 40) {
        const float* wr = wc2 + (size_t)tid * 80;
        float acc = bc2[tid];
#pragma unroll
        for (int u = 0; u < 80; ++u) acc += hc[u] * wr[u];
        out[(size_t)row * 40 + tid] = acc;
    } else if (tid >= 64 && tid < 66) {
        int j = tid - 64;
        const float* wr = wb2 + (size_t)j * 80;
        float acc = bb2[j];
#pragma unroll
        for (int u = 0; u < 80; ++u) acc += hb[u] * wr[u];
        out[OFF_BIN + (size_t)row * 2 + j] = acc;
    }
}

// ---------------- pairwise scores, written transposed: scT[b][e][d] = scores[b][d][e]
// block = (b, e, d-tile of 64); wave = u-group (25 u each), lane = d within tile
__global__ __launch_bounds__(256) void k_scores(const float* __restrict__ cum,
                                                const float* __restrict__ ws1,
                                                const float* __restrict__ ws2,
                                                const float* __restrict__ bs2,
                                                const float* __restrict__ Pd,
                                                const float* __restrict__ Pe,
                                                const float* a_s0p, const float* a_s1p,
                                                float* __restrict__ scT) {
    int bid = blockIdx.x;
    int dt = bid & 3, e = (bid >> 2) & 255, b = bid >> 10;
    int d0 = dt << 6;
    int tid = threadIdx.x;
    __shared__ float cume[256];
    __shared__ float Y[64 * 257];
    __shared__ float red[4][64];
    float a0 = a_s0p[0], a1 = a_s1p[0];
    cume[tid] = cum[(size_t)(((b << 8) + e) << 8) + tid];
    __syncthreads();
#pragma unroll 4
    for (int dj = 0; dj < 64; ++dj) {
        float cd = cum[(size_t)(((b << 8) + (d0 + dj)) << 8) + tid];
        Y[dj * 257 + tid] = preluf(cume[tid] - cd, a0);
    }
    __syncthreads();
    int ug = __builtin_amdgcn_readfirstlane(tid >> 6);  // wave-uniform u-group 0..3
    int ld = tid & 63;
    int d = d0 + ld;
    float acc[25];
#pragma unroll
    for (int t = 0; t < 25; ++t) acc[t] = 0.f;
    const float* wc = ws1 + (size_t)(ug * 25) * 768;  // c-block columns are [0,256)
#pragma unroll 4
    for (int k = 0; k < 256; ++k) {
        float y = Y[ld * 257 + k];
#pragma unroll
        for (int t = 0; t < 25; ++t) acc[t] += y * wc[(size_t)t * 768 + k];
    }
    const float* pdrow = Pd + (size_t)((b << 8) + d) * 100;
    const float* perow = Pe + (size_t)((b << 8) + e) * 100;
    float part = 0.f;
#pragma unroll
    for (int t = 0; t < 25; ++t) {
        int u = ug * 25 + t;
        float h = acc[t] + pdrow[u] + perow[u];
        part += preluf(h, a1) * ws2[u];
    }
    red[ug][ld] = part;
    __syncthreads();
    if (tid < 64) {
        float s = red[0][tid] + red[1][tid] + red[2][tid] + red[3][tid] + bs2[0];
        scT[(size_t)(((b << 8) + e) << 8) + d0 + tid] = s;
    }
}

// ---------------- banded DP + backtrack (fused). pred_scores[b] == best[b][len-1].
__global__ __launch_bounds__(128) void k_dp(const float* __restrict__ scT,
                                            const int* __restrict__ lengths,
                                            float* __restrict__ out) {
    __shared__ float best[2][256];
    __shared__ int bp[2][256];
    __shared__ float bm[2][256];
    int tid = threadIdx.x;
    for (int i = tid; i < 512; i += 128) {
        ((float*)best)[i] = 0.f;
        ((int*)bp)[i] = 0;
        ((float*)bm)[i] = 0.f;
    }
    __syncthreads();
    int b = tid >> 6, ln = tid & 63;
    const float* sb = scT + ((size_t)b << 16);
    for (int i = 1; i < 256; ++i) {
        int start = (i > 64) ? (i - 64) : 0;
        int j = start + ln;
        float v = -1000000000.0f;
        int ki = j;
        if (j < i) v = best[b][j] + sb[(i << 8) + j];
#pragma unroll
        for (int off = 32; off > 0; off >>= 1) {
            float ov = __shfl_down(v, off);
            int ok = __shfl_down(ki, off);
            if (ov > v || (ov == v && ok < ki)) { v = ov; ki = ok; }
        }
        if (ln == 0) { best[b][i] = v; bp[b][i] = ki; }
        // within-wave LDS ordering guarantees visibility for next iteration
    }
    __syncthreads();
    if (tid < 2) {
        int bb = tid;
        int cur = lengths[bb] - 1;
        out[OFF_PRED + bb] = best[bb][cur];
        for (int it = 0; it < 256; ++it) {
            bm[bb][cur] = 1.f;
            int prev = bp[bb][cur];
            cur = (cur > 0) ? prev : 0;
        }
    }
    __syncthreads();
    for (int i = tid; i < 512; i += 128) out[OFF_BM + i] = ((float*)bm)[i];
}

extern "C" void kernel_launch(void* const* d_in, const int* in_sizes, int n_in,
                              void* d_out, int out_size, void* d_ws, size_t ws_size,
                              hipStream_t stream) {
    const float* x     = (const float*)d_in[0];
    const int* lengths = (const int*)d_in[1];
    const float* wih0f = (const float*)d_in[2];
    const float* whh0f = (const float*)d_in[3];
    const float* b0f   = (const float*)d_in[4];
    const float* wih0b = (const float*)d_in[5];
    const float* whh0b = (const float*)d_in[6];
    const float* b0b   = (const float*)d_in[7];
    const float* wih1f = (const float*)d_in[8];
    const float* whh1f = (const float*)d_in[9];
    const float* b1f   = (const float*)d_in[10];
    const float* wih1b = (const float*)d_in[11];
    const float* whh1b = (const float*)d_in[12];
    const float* b1b   = (const float*)d_in[13];
    const float* a_s0  = (const float*)d_in[14];
    const float* w_s1  = (const float*)d_in[15];
    const float* b_s1  = (const float*)d_in[16];
    const float* a_s1  = (const float*)d_in[17];
    const float* w_s2  = (const float*)d_in[18];
    const float* b_s2  = (const float*)d_in[19];
    const float* a_c0  = (const float*)d_in[20];
    const float* w_c1  = (const float*)d_in[21];
    const float* b_c1  = (const float*)d_in[22];
    const float* a_c1  = (const float*)d_in[23];
    const float* w_c2  = (const float*)d_in[24];
    const float* b_c2  = (const float*)d_in[25];
    const float* a_b0  = (const float*)d_in[26];
    const float* w_b1  = (const float*)d_in[27];
    const float* b_b1  = (const float*)d_in[28];
    const float* a_b1  = (const float*)d_in[29];
    const float* w_b2  = (const float*)d_in[30];
    const float* b_b2  = (const float*)d_in[31];

    float* wsf = (float*)d_ws;
    float* preF = wsf;                 // 262144
    float* preB = wsf + 262144;        // 262144
    float* h0f  = wsf + 524288;        // 65536
    float* h0b  = wsf + 589824;        // 65536
    float* h1f  = wsf + 655360;        // 65536
    float* h1b  = wsf + 720896;        // 65536
    float* rnn  = wsf + 786432;        // 131072
    float* cum  = wsf + 917504;        // 131072
    float* Pd   = wsf + 1048576;       // 51200
    float* Pe   = wsf + 1099776;       // 51200
    float* scT  = wsf + 1150976;       // 131072  (total 5.13 MB)
    float* out  = (float*)d_out;

    // layer 0
    k_pre<<<128, 256, 0, stream>>>(x, x, 80, 80, wih0f, b0f, preF);
    k_pre<<<128, 256, 0, stream>>>(x, x, 80, 80, wih0b, b0b, preB);
    k_lstm<<<4, 512, 0, stream>>>(preF, preB, whh0f, whh0b, h0f, h0b);
    // layer 1
    k_pre<<<128, 256, 0, stream>>>(h0f, h0b, 128, 256, wih1f, b1f, preF);
    k_pre<<<128, 256, 0, stream>>>(h0f, h0b, 128, 256, wih1b, b1b, preB);
    k_lstm<<<4, 512, 0, stream>>>(preF, preB, whh1f, whh1b, h1f, h1b);
    // features
    k_cum<<<2, 256, 0, stream>>>(h1f, h1b, rnn, cum);
    k_pde<<<512, 256, 0, stream>>>(rnn, w_s1, b_s1, a_s0, Pd, Pe);
    k_head<<<512, 256, 0, stream>>>(rnn, a_c0, w_c1, b_c1, a_c1, w_c2, b_c2,
                                    a_b0, w_b1, b_b1, a_b1, w_b2, b_b2, out);
    // pairwise scores
    k_scores<<<2048, 256, 0, stream>>>(cum, w_s1, w_s2, b_s2, Pd, Pe, a_s0, a_s1, scT);
    // DP + backtrack
    k_dp<<<1, 128, 0, stream>>>(scT, lengths, out);
}

// Round 6
// 1043.600 us; speedup vs baseline: 1.1392x; 1.1392x over previous
//
#include <hip/hip_runtime.h>
#include <math.h>

// Problem constants: B=2, S=256, IN=80, H=128, NC=40, WSEG=64, F2=256
// Output layout (floats): cls_out[2*256*40]=20480 @0, bin_out[2*256*2]=1024 @20480,
//                         bmask[2*256]=512 @21504, pred_scores[2] @22016

#define OFF_BIN 20480
#define OFF_BM  21504
#define OFF_PRED 22016

__device__ __forceinline__ float preluf(float x, float a) { return x >= 0.f ? x : a * x; }
__device__ __forceinline__ float sigf(float x) { return 1.f / (1.f + __expf(-x)); }

// ---------------- input projection (both dirs of one layer):
// pre{F,B}[t*2+b][g] = bias[g] + sum_k in(b,t,k)*W[g][k]
// in(b,t,k) = k<Adim ? A[((b*256)+t)*Adim+k] : B[((b*256)+t)*(K-Adim)+(k-Adim)]
// 128 blocks x 256 thr; block = 4 (t,b) rows; thread = 4 gate rows (f:g,g+256, b:g,g+256)
__global__ __launch_bounds__(256) void k_pre2(const float* __restrict__ A,
                                              const float* __restrict__ B,
                                              int Adim, int K,
                                              const float* __restrict__ wf,
                                              const float* __restrict__ bf,
                                              const float* __restrict__ wb,
                                              const float* __restrict__ bb,
                                              float* __restrict__ outF,
                                              float* __restrict__ outB) {
    __shared__ __align__(16) float xs[4 * 256];
    int r0 = blockIdx.x << 2;
    int tid = threadIdx.x;
    int Bdim = K - Adim;
    for (int e = tid; e < 4 * K; e += 256) {
        int row = e / K, kk = e - row * K;
        int tb = r0 + row; int t = tb >> 1, b = tb & 1;
        float v = (kk < Adim) ? A[(size_t)((b << 8) + t) * Adim + kk]
                              : B[(size_t)((b << 8) + t) * Bdim + (kk - Adim)];
        xs[row * K + kk] = v;
    }
    __syncthreads();
    int g = tid;
    const float* w0 = wf + (size_t)g * K;
    const float* w1 = wf + (size_t)(g + 256) * K;
    const float* w2 = wb + (size_t)g * K;
    const float* w3 = wb + (size_t)(g + 256) * K;
    float acc0[4], acc1[4], acc2[4], acc3[4];
    float b0v = bf[g], b1v = bf[g + 256], b2v = bb[g], b3v = bb[g + 256];
#pragma unroll
    for (int r = 0; r < 4; ++r) { acc0[r] = b0v; acc1[r] = b1v; acc2[r] = b2v; acc3[r] = b3v; }
    for (int k = 0; k < K; k += 4) {
        float4 wq0 = *(const float4*)(w0 + k);
        float4 wq1 = *(const float4*)(w1 + k);
        float4 wq2 = *(const float4*)(w2 + k);
        float4 wq3 = *(const float4*)(w3 + k);
#pragma unroll
        for (int r = 0; r < 4; ++r) {
            float4 xq = *(const float4*)(xs + r * K + k);
            acc0[r] += wq0.x * xq.x + wq0.y * xq.y + wq0.z * xq.z + wq0.w * xq.w;
            acc1[r] += wq1.x * xq.x + wq1.y * xq.y + wq1.z * xq.z + wq1.w * xq.w;
            acc2[r] += wq2.x * xq.x + wq2.y * xq.y + wq2.z * xq.z + wq2.w * xq.w;
            acc3[r] += wq3.x * xq.x + wq3.y * xq.y + wq3.z * xq.z + wq3.w * xq.w;
        }
    }
#pragma unroll
    for (int r = 0; r < 4; ++r) {
        int tb = r0 + r;
        outF[(size_t)tb * 512 + g]       = acc0[r];
        outF[(size_t)tb * 512 + 256 + g] = acc1[r];
        outB[(size_t)tb * 512 + g]       = acc2[r];
        outB[(size_t)tb * 512 + 256 + g] = acc3[r];
    }
}

// ---------------- LSTM scan (R3 version, best measured): one block per (dir, batch).
// 512 threads = (k-chunk c = tid>>7, unit gg = tid&127); G=4 gates/thread over a
// 32-wide k-chunk; h broadcast from LDS (wave-uniform float4 reads, conflict-free).
__global__ __launch_bounds__(512, 2) void k_lstm(const float* __restrict__ pre_f,
                                                 const float* __restrict__ pre_b,
                                                 const float* __restrict__ whh_f,
                                                 const float* __restrict__ whh_b,
                                                 float* __restrict__ hout_f,
                                                 float* __restrict__ hout_b) {
    const int dir = blockIdx.x >> 1;
    const int b = blockIdx.x & 1;
    const float* pre = dir ? pre_b : pre_f;
    const float* whh = dir ? whh_b : whh_f;
    float* hout = dir ? hout_b : hout_f;
    const int tid = threadIdx.x;
    const int c = tid >> 7;        // k-chunk 0..3 (wave-uniform)
    const int gg = tid & 127;      // hidden unit 0..127
    const int k0 = c << 5;

    float w[4][32];
#pragma unroll
    for (int j = 0; j < 4; ++j) {
#pragma unroll
        for (int k = 0; k < 32; k += 4) {
            float4 v = *(const float4*)(whh + (size_t)((j << 7) + gg) * 128 + k0 + k);
            w[j][k] = v.x; w[j][k + 1] = v.y; w[j][k + 2] = v.z; w[j][k + 3] = v.w;
        }
    }

    __shared__ float hl[128];
    __shared__ float4 part[4][128];
    if (tid < 128) hl[tid] = 0.f;
    float cst = 0.f;
    __syncthreads();

    int t0 = dir ? 255 : 0;
    float p0 = 0.f, p1 = 0.f, p2 = 0.f, p3 = 0.f;
    if (tid < 128) {
        const float* pp = pre + ((size_t)t0 * 2 + b) * 512;
        p0 = pp[gg]; p1 = pp[128 + gg]; p2 = pp[256 + gg]; p3 = pp[384 + gg];
    }

    for (int step = 0; step < 256; ++step) {
        int t = dir ? (255 - step) : step;
        float n0 = 0.f, n1 = 0.f, n2 = 0.f, n3 = 0.f;
        if (step < 255 && tid < 128) {
            int tn = dir ? (254 - step) : (step + 1);
            const float* pp = pre + ((size_t)tn * 2 + b) * 512;
            n0 = pp[gg]; n1 = pp[128 + gg]; n2 = pp[256 + gg]; n3 = pp[384 + gg];
        }
        float a0 = 0.f, a1 = 0.f, a2 = 0.f, a3 = 0.f;
#pragma unroll
        for (int k = 0; k < 32; k += 4) {
            float4 h4 = *(const float4*)(hl + k0 + k);   // wave-uniform broadcast
            a0 += w[0][k] * h4.x + w[0][k + 1] * h4.y + w[0][k + 2] * h4.z + w[0][k + 3] * h4.w;
            a1 += w[1][k] * h4.x + w[1][k + 1] * h4.y + w[1][k + 2] * h4.z + w[1][k + 3] * h4.w;
            a2 += w[2][k] * h4.x + w[2][k + 1] * h4.y + w[2][k + 2] * h4.z + w[2][k + 3] * h4.w;
            a3 += w[3][k] * h4.x + w[3][k + 1] * h4.y + w[3][k + 2] * h4.z + w[3][k + 3] * h4.w;
        }
        part[c][gg] = make_float4(a0, a1, a2, a3);
        __syncthreads();
        if (tid < 128) {
            float4 q0 = part[0][gg], q1 = part[1][gg], q2 = part[2][gg], q3 = part[3][gg];
            float gi = p0 + ((q0.x + q1.x) + (q2.x + q3.x));
            float gf = p1 + ((q0.y + q1.y) + (q2.y + q3.y));
            float gG = p2 + ((q0.z + q1.z) + (q2.z + q3.z));
            float go = p3 + ((q0.w + q1.w) + (q2.w + q3.w));
            cst = sigf(gf) * cst + sigf(gi) * tanhf(gG);
            float h = sigf(go) * tanhf(cst);
            hl[gg] = h;
            hout[(size_t)(((b << 8) + t) << 7) + gg] = h;
            p0 = n0; p1 = n1; p2 = n2; p3 = n3;
        }
        __syncthreads();
    }
}

// ---------------- concat layer-1 dirs -> rnn, cumsum over time -> cum
__global__ __launch_bounds__(256) void k_cum(const float* __restrict__ h1f,
                                             const float* __restrict__ h1b,
                                             float* __restrict__ rnn,
                                             float* __restrict__ cum) {
    int b = blockIdx.x, k = threadIdx.x;
    const float* src = (k < 128) ? h1f : h1b;
    int kk = k & 127;
    float run = 0.f;
#pragma unroll 8
    for (int t = 0; t < 256; ++t) {
        float v = src[(size_t)(((b << 8) + t) << 7) + kk];
        size_t o = (size_t)(((b << 8) + t) << 8) + k;
        rnn[o] = v;
        run += v;
        cum[o] = run;
    }
}

// ---------------- Pd[b,i,u] = b_s1[u] + prelu(rnn[b,i],a0) . W1[u, 256:512]
//                  Pe[b,j,u] =           prelu(rnn[b,j],a0) . W1[u, 512:768]
__global__ __launch_bounds__(256) void k_pde(const float* __restrict__ rnn,
                                             const float* __restrict__ ws1,
                                             const float* __restrict__ bs1,
                                             const float* __restrict__ a_s0,
                                             float* __restrict__ Pd,
                                             float* __restrict__ Pe) {
    int row = blockIdx.x;  // b*256+s
    __shared__ __align__(16) float pr[256];
    float a0 = a_s0[0];
    float v = rnn[(size_t)row * 256 + threadIdx.x];
    pr[threadIdx.x] = preluf(v, a0);
    __syncthreads();
    int t = threadIdx.x;
    const float4* p4 = (const float4*)pr;
    if (t < 100) {
        const float4* wr = (const float4*)(ws1 + (size_t)t * 768 + 256);
        float acc = bs1[t];
#pragma unroll 8
        for (int q = 0; q < 64; ++q) {
            float4 w4 = wr[q], x4 = p4[q];
            acc += w4.x * x4.x + w4.y * x4.y + w4.z * x4.z + w4.w * x4.w;
        }
        Pd[(size_t)row * 100 + t] = acc;
    } else if (t >= 128 && t < 228) {
        int u = t - 128;
        const float4* wr = (const float4*)(ws1 + (size_t)u * 768 + 512);
        float acc = 0.f;
#pragma unroll 8
        for (int q = 0; q < 64; ++q) {
            float4 w4 = wr[q], x4 = p4[q];
            acc += w4.x * x4.x + w4.y * x4.y + w4.z * x4.z + w4.w * x4.w;
        }
        Pe[(size_t)row * 100 + u] = acc;
    }
}

// ---------------- cls / bin heads
__global__ __launch_bounds__(256) void k_head(const float* __restrict__ rnn,
                                              const float* ac0p, const float* __restrict__ wc1,
                                              const float* __restrict__ bc1, const float* ac1p,
                                              const float* __restrict__ wc2, const float* __restrict__ bc2,
                                              const float* ab0p, const float* __restrict__ wb1,
                                              const float* __restrict__ bb1, const float* ab1p,
                                              const float* __restrict__ wb2, const float* __restrict__ bb2,
                                              float* __restrict__ out) {
    int row = blockIdx.x;  // b*256+s
    int tid = threadIdx.x;
    __shared__ __align__(16) float xc[256];
    __shared__ __align__(16) float xb[256];
    __shared__ __align__(16) float hc[80];
    __shared__ __align__(16) float hb[80];
    float ac0 = ac0p[0], ac1 = ac1p[0], ab0 = ab0p[0], ab1 = ab1p[0];
    float v = rnn[(size_t)row * 256 + tid];
    xc[tid] = preluf(v, ac0);
    xb[tid] = preluf(v, ab0);
    __syncthreads();
    if (tid < 80) {
        const float4* wr = (const float4*)(wc1 + (size_t)tid * 256);
        const float4* x4 = (const float4*)xc;
        float acc = bc1[tid];
#pragma unroll 8
        for (int q = 0; q < 64; ++q) {
            float4 w4 = wr[q], p = x4[q];
            acc += w4.x * p.x + w4.y * p.y + w4.z * p.z + w4.w * p.w;
        }
        hc[tid] = preluf(acc, ac1);
    } else if (tid >= 128 && tid < 208) {
        int u = tid - 128;
        const float4* wr = (const float4*)(wb1 + (size_t)u * 256);
        const float4* x4 = (const float4*)xb;
        float acc = bb1[u];
#pragma unroll 8
        for (int q = 0; q < 64; ++q) {
            float4 w4 = wr[q], p = x4[q];
            acc += w4.x * p.x + w4.y * p.y + w4.z * p.z + w4.w * p.w;
        }
        hb[u] = preluf(acc, ab1);
    }
    __syncthreads();
    if (tid < 40) {
        const float4* wr = (const float4*)(wc2 + (size_t)tid * 80);
        const float4* h4 = (const float4*)hc;
        float acc = bc2[tid];
#pragma unroll
        for (int q = 0; q < 20; ++q) {
            float4 w4 = wr[q], p = h4[q];
            acc += w4.x * p.x + w4.y * p.y + w4.z * p.z + w4.w * p.w;
        }
        out[(size_t)row * 40 + tid] = acc;
    } else if (tid >= 64 && tid < 66) {
        int j = tid - 64;
        const float4* wr = (const float4*)(wb2 + (size_t)j * 80);
        const float4* h4 = (const float4*)hb;
        float acc = bb2[j];
#pragma unroll
        for (int q = 0; q < 20; ++q) {
            float4 w4 = wr[q], p = h4[q];
            acc += w4.x * p.x + w4.y * p.y + w4.z * p.z + w4.w * p.w;
        }
        out[OFF_BIN + (size_t)row * 2 + j] = acc;
    }
}

// ---------------- pairwise scores, written transposed: scT[b][e][d] = scores[b][d][e]
// block = (b, e, d-tile of 64); wave = u-group (25 u each), lane = d within tile.
// W loads are wave-uniform float4 (ug via readfirstlane) -> s_load_dwordx4.
__global__ __launch_bounds__(256) void k_scores(const float* __restrict__ cum,
                                                const float* __restrict__ ws1,
                                                const float* __restrict__ ws2,
                                                const float* __restrict__ bs2,
                                                const float* __restrict__ Pd,
                                                const float* __restrict__ Pe,
                                                const float* a_s0p, const float* a_s1p,
                                                float* __restrict__ scT) {
    int bid = blockIdx.x;
    int dt = bid & 3, e = (bid >> 2) & 255, b = bid >> 10;
    int d0 = dt << 6;
    int tid = threadIdx.x;
    __shared__ float cume[256];
    __shared__ float Y[64 * 257];
    __shared__ float red[4][64];
    float a0 = a_s0p[0], a1 = a_s1p[0];
    cume[tid] = cum[(size_t)(((b << 8) + e) << 8) + tid];
    __syncthreads();
#pragma unroll 4
    for (int dj = 0; dj < 64; ++dj) {
        float cd = cum[(size_t)(((b << 8) + (d0 + dj)) << 8) + tid];
        Y[dj * 257 + tid] = preluf(cume[tid] - cd, a0);
    }
    __syncthreads();
    int ug = __builtin_amdgcn_readfirstlane(tid >> 6);  // wave-uniform u-group 0..3
    int ld = tid & 63;
    int d = d0 + ld;
    float acc[25];
#pragma unroll
    for (int t = 0; t < 25; ++t) acc[t] = 0.f;
    const float* wc = ws1 + (size_t)(ug * 25) * 768;  // c-block columns are [0,256)
    const float* yrow = Y + ld * 257;
    for (int k = 0; k < 256; k += 4) {
        float y0 = yrow[k], y1 = yrow[k + 1], y2 = yrow[k + 2], y3 = yrow[k + 3];
#pragma unroll
        for (int t = 0; t < 25; ++t) {
            float4 wq = *(const float4*)(wc + (size_t)t * 768 + k);  // uniform -> s_load
            acc[t] += y0 * wq.x + y1 * wq.y + y2 * wq.z + y3 * wq.w;
        }
    }
    const float* pdrow = Pd + (size_t)((b << 8) + d) * 100;
    const float* perow = Pe + (size_t)((b << 8) + e) * 100;
    float part = 0.f;
#pragma unroll
    for (int t = 0; t < 25; ++t) {
        int u = ug * 25 + t;
        float h = acc[t] + pdrow[u] + perow[u];
        part += preluf(h, a1) * ws2[u];
    }
    red[ug][ld] = part;
    __syncthreads();
    if (tid < 64) {
        float s = red[0][tid] + red[1][tid] + red[2][tid] + red[3][tid] + bs2[0];
        scT[(size_t)(((b << 8) + e) << 8) + d0 + tid] = s;
    }
}

// ---------------- banded DP + backtrack (fused). pred_scores[b] == best[b][len-1].
// Score row for step i+1 is prefetched while step i reduces (hides L2 latency).
__global__ __launch_bounds__(128) void k_dp(const float* __restrict__ scT,
                                            const int* __restrict__ lengths,
                                            float* __restrict__ out) {
    __shared__ float best[2][256];
    __shared__ int bp[2][256];
    __shared__ float bm[2][256];
    int tid = threadIdx.x;
    for (int i = tid; i < 512; i += 128) {
        ((float*)best)[i] = 0.f;
        ((int*)bp)[i] = 0;
        ((float*)bm)[i] = 0.f;
    }
    __syncthreads();
    int b = tid >> 6, ln = tid & 63;
    const float* sb = scT + ((size_t)b << 16);
    float sc_next = sb[(1 << 8) + ln];   // i=1, start=0
    for (int i = 1; i < 256; ++i) {
        float sc = sc_next;
        if (i < 255) {
            int i2 = i + 1;
            int st2 = (i2 > 64) ? (i2 - 64) : 0;
            sc_next = sb[(i2 << 8) + st2 + ln];
        }
        int start = (i > 64) ? (i - 64) : 0;
        int j = start + ln;
        float v = -1000000000.0f;
        int ki = j;
        if (j < i) v = best[b][j] + sc;
#pragma unroll
        for (int off = 32; off > 0; off >>= 1) {
            float ov = __shfl_down(v, off);
            int ok = __shfl_down(ki, off);
            if (ov > v || (ov == v && ok < ki)) { v = ov; ki = ok; }
        }
        if (ln == 0) { best[b][i] = v; bp[b][i] = ki; }
        // within-wave LDS ordering guarantees visibility for next iteration
    }
    __syncthreads();
    if (tid < 2) {
        int bb = tid;
        int cur = lengths[bb] - 1;
        out[OFF_PRED + bb] = best[bb][cur];
        for (int it = 0; it < 256; ++it) {
            bm[bb][cur] = 1.f;
            int prev = bp[bb][cur];
            cur = (cur > 0) ? prev : 0;
        }
    }
    __syncthreads();
    for (int i = tid; i < 512; i += 128) out[OFF_BM + i] = ((float*)bm)[i];
}

extern "C" void kernel_launch(void* const* d_in, const int* in_sizes, int n_in,
                              void* d_out, int out_size, void* d_ws, size_t ws_size,
                              hipStream_t stream) {
    const float* x     = (const float*)d_in[0];
    const int* lengths = (const int*)d_in[1];
    const float* wih0f = (const float*)d_in[2];
    const float* whh0f = (const float*)d_in[3];
    const float* b0f   = (const float*)d_in[4];
    const float* wih0b = (const float*)d_in[5];
    const float* whh0b = (const float*)d_in[6];
    const float* b0b   = (const float*)d_in[7];
    const float* wih1f = (const float*)d_in[8];
    const float* whh1f = (const float*)d_in[9];
    const float* b1f   = (const float*)d_in[10];
    const float* wih1b = (const float*)d_in[11];
    const float* whh1b = (const float*)d_in[12];
    const float* b1b   = (const float*)d_in[13];
    const float* a_s0  = (const float*)d_in[14];
    const float* w_s1  = (const float*)d_in[15];
    const float* b_s1  = (const float*)d_in[16];
    const float* a_s1  = (const float*)d_in[17];
    const float* w_s2  = (const float*)d_in[18];
    const float* b_s2  = (const float*)d_in[19];
    const float* a_c0  = (const float*)d_in[20];
    const float* w_c1  = (const float*)d_in[21];
    const float* b_c1  = (const float*)d_in[22];
    const float* a_c1  = (const float*)d_in[23];
    const float* w_c2  = (const float*)d_in[24];
    const float* b_c2  = (const float*)d_in[25];
    const float* a_b0  = (const float*)d_in[26];
    const float* w_b1  = (const float*)d_in[27];
    const float* b_b1  = (const float*)d_in[28];
    const float* a_b1  = (const float*)d_in[29];
    const float* w_b2  = (const float*)d_in[30];
    const float* b_b2  = (const float*)d_in[31];

    float* wsf = (float*)d_ws;
    float* preF = wsf;                 // 262144
    float* preB = wsf + 262144;        // 262144
    float* h0f  = wsf + 524288;        // 65536
    float* h0b  = wsf + 589824;        // 65536
    float* h1f  = wsf + 655360;        // 65536
    float* h1b  = wsf + 720896;        // 65536
    float* rnn  = wsf + 786432;        // 131072
    float* cum  = wsf + 917504;        // 131072
    float* Pd   = wsf + 1048576;       // 51200
    float* Pe   = wsf + 1099776;       // 51200
    float* scT  = wsf + 1150976;       // 131072  (total 5.13 MB)
    float* out  = (float*)d_out;

    // layer 0 (both dirs fused)
    k_pre2<<<128, 256, 0, stream>>>(x, x, 80, 80, wih0f, b0f, wih0b, b0b, preF, preB);
    k_lstm<<<4, 512, 0, stream>>>(preF, preB, whh0f, whh0b, h0f, h0b);
    // layer 1 (both dirs fused)
    k_pre2<<<128, 256, 0, stream>>>(h0f, h0b, 128, 256, wih1f, b1f, wih1b, b1b, preF, preB);
    k_lstm<<<4, 512, 0, stream>>>(preF, preB, whh1f, whh1b, h1f, h1b);
    // features
    k_cum<<<2, 256, 0, stream>>>(h1f, h1b, rnn, cum);
    k_pde<<<512, 256, 0, stream>>>(rnn, w_s1, b_s1, a_s0, Pd, Pe);
    k_head<<<512, 256, 0, stream>>>(rnn, a_c0, w_c1, b_c1, a_c1, w_c2, b_c2,
                                    a_b0, w_b1, b_b1, a_b1, w_b2, b_b2, out);
    // pairwise scores
    k_scores<<<2048, 256, 0, stream>>>(cum, w_s1, w_s2, b_s2, Pd, Pe, a_s0, a_s1, scT);
    // DP + backtrack
    k_dp<<<1, 128, 0, stream>>>(scT, lengths, out);
}